// Round 17
// baseline (6625.621 us; speedup 1.0000x reference)
//
#include <hip/hip_runtime.h>
#include <cmath>

namespace {

constexpr int BB = 32, TT = 256, HH = 128;
constexpr int PB = 2048;                   // B*P
constexpr int WGPB = 8;                    // workgroups per batch
constexpr double INV_P = 0.0078125;        // (1-alpha)/P
constexpr float LOG_P0 = -4.1588830833596715f;  // log(1/64)

__device__ __forceinline__ float sigf(float x) { return 1.f / (1.f + expf(-x)); }

// coherent (agent-scope, non-invalidating/non-flushing) ops for cross-WG data
__device__ __forceinline__ float ldc(const float* p) {
  return __hip_atomic_load(p, __ATOMIC_RELAXED, __HIP_MEMORY_SCOPE_AGENT);
}
__device__ __forceinline__ double ldc(const double* p) {
  return __hip_atomic_load(p, __ATOMIC_RELAXED, __HIP_MEMORY_SCOPE_AGENT);
}
__device__ __forceinline__ void stc(unsigned long long* p, unsigned long long v) {
  __hip_atomic_store(p, v, __ATOMIC_RELAXED, __HIP_MEMORY_SCOPE_AGENT);
}
__device__ __forceinline__ void stc(double* p, double v) {
  __hip_atomic_store(p, v, __ATOMIC_RELAXED, __HIP_MEMORY_SCOPE_AGENT);
}

// ---- pack: WzrH[k][c] (k<128, c<256), WnH[k][c] ----
__global__ void pack_kernel(const float* __restrict__ Wz, const float* __restrict__ Wr,
                            const float* __restrict__ Wn,
                            float* __restrict__ WzrH, float* __restrict__ WnH) {
  int tid = blockIdx.x * blockDim.x + threadIdx.x;
  int stride = gridDim.x * blockDim.x;
  for (int i = tid; i < 128 * 256; i += stride) {
    int k = i >> 8, c = i & 255;
    WzrH[i] = (c < 128) ? Wz[k * 128 + c] : Wr[k * 128 + (c - 128)];
    WnH[i] = Wn[k * 256 + c];
  }
}

// -------------------- encode: convs + map/meas/mot embeddings -> emb[b][t][128] ----
__global__ __launch_bounds__(256) void encode_kernel(
    const float* __restrict__ map_in, const float* __restrict__ meas_in,
    const float* __restrict__ mot_in,
    const float* __restrict__ c1w, const float* __restrict__ c2w, const float* __restrict__ c3w,
    const float* __restrict__ Wme, const float* __restrict__ bme,
    const float* __restrict__ Wmm, const float* __restrict__ bmm,
    const float* __restrict__ Wmo, const float* __restrict__ bmo,
    const float* __restrict__ Wms, const float* __restrict__ bms,
    const float* __restrict__ Wmt, const float* __restrict__ bmt,
    float* __restrict__ emb) {
  const int b = blockIdx.x;
  const int tid = threadIdx.x;
  __shared__ float ml[324];
  __shared__ float o1[16 * 81];
  __shared__ float o2[32 * 81];
  __shared__ float o3[32 * 81];
  __shared__ float em[128];
  __shared__ float mm[64];
  __shared__ float mo[64];

  for (int i = tid; i < 324; i += 256) ml[i] = map_in[b * 324 + i];
  __syncthreads();
  for (int oid = tid; oid < 16 * 81; oid += 256) {
    int c = oid / 81, r = oid % 81, i = r / 9, j = r % 9;
    float acc = 0.f;
    for (int u = 0; u < 5; ++u) {
      int ii = 2 * i - 2 + u;
      if (ii < 0 || ii >= 18) continue;
      for (int v = 0; v < 5; ++v) {
        int jj = 2 * j - 2 + v;
        if (jj < 0 || jj >= 18) continue;
        acc += ml[ii * 18 + jj] * c1w[c * 25 + u * 5 + v];
      }
    }
    o1[oid] = fmaxf(acc, 0.f);
  }
  __syncthreads();
  for (int oid = tid; oid < 32 * 81; oid += 256) {
    int c = oid / 81, r = oid % 81, i = r / 9, j = r % 9;
    float acc = 0.f;
    for (int ci = 0; ci < 16; ++ci)
      for (int u = 0; u < 3; ++u) {
        int ii = i + u - 1;
        if (ii < 0 || ii >= 9) continue;
        for (int v = 0; v < 3; ++v) {
          int jj = j + v - 1;
          if (jj < 0 || jj >= 9) continue;
          acc += o1[ci * 81 + ii * 9 + jj] * c2w[((c * 16 + ci) * 3 + u) * 3 + v];
        }
      }
    o2[oid] = fmaxf(acc, 0.f);
  }
  __syncthreads();
  for (int oid = tid; oid < 32 * 81; oid += 256) {
    int c = oid / 81, r = oid % 81, i = r / 9, j = r % 9;
    float acc = 0.f;
    for (int ci = 0; ci < 32; ++ci)
      for (int u = 0; u < 3; ++u) {
        int ii = i + u - 1;
        if (ii < 0 || ii >= 9) continue;
        for (int v = 0; v < 3; ++v) {
          int jj = j + v - 1;
          if (jj < 0 || jj >= 9) continue;
          acc += o2[ci * 81 + ii * 9 + jj] * c3w[((c * 32 + ci) * 3 + u) * 3 + v];
        }
      }
    o3[oid] = fmaxf(acc, 0.f);
  }
  __syncthreads();
  if (tid < 128) {
    float acc = 0.f;
    for (int k = 0; k < 2592; ++k) acc += o3[k] * Wme[k * 128 + tid];
    em[tid] = fmaxf(acc + bme[tid], 0.f);
  }
  __syncthreads();
  if (tid < 64) {
    float a1 = 0.f, a2 = 0.f;
    for (int k = 0; k < 128; ++k) {
      a1 += em[k] * Wmm[k * 64 + tid];
      a2 += em[k] * Wmo[k * 64 + tid];
    }
    mm[tid] = fmaxf(a1 + bmm[tid], 0.f);
    mo[tid] = fmaxf(a2 + bmo[tid], 0.f);
  }
  __syncthreads();
  {
    int c = tid & 127;
    for (int t = tid >> 7; t < TT; t += 2) {
      float e;
      if (c < 64) {
        float acc = 0.f;
        for (int m = 0; m < 16; ++m) acc += meas_in[(size_t)(b * TT + t) * 16 + m] * Wms[m * 64 + c];
        e = fmaxf(acc + bms[c], 0.f) * mm[c];
      } else {
        int c2 = c - 64;
        float acc = 0.f;
        for (int m = 0; m < 3; ++m) acc += mot_in[(size_t)(b * TT + t) * 3 + m] * Wmt[m * 64 + c2];
        e = fmaxf(acc + bmt[c2], 0.f) * mo[c2];
      }
      emb[(size_t)(b * TT + t) * 128 + c] = e;
    }
  }
}

// ---------- xdot: per-(t,b) x-part of each GEMM column + bias -> xdot[t][b][516] ----
__global__ __launch_bounds__(128) void xdot_kernel(
    const float* __restrict__ emb, const float* __restrict__ Wz, const float* __restrict__ Wr,
    const float* __restrict__ Wn, const float* __restrict__ bz, const float* __restrict__ br,
    const float* __restrict__ bn, const float* __restrict__ Wo, const float* __restrict__ bo,
    float* __restrict__ xdot) {
  const int b = blockIdx.y;
  const int t0 = blockIdx.x * 8;
  __shared__ float xl[8][132];
  for (int i = threadIdx.x; i < 8 * 128; i += 128) {
    int r = i >> 7, d = i & 127;
    xl[r][d] = emb[(size_t)(b * TT + t0 + r) * 128 + d];
  }
  __syncthreads();
  const int c = threadIdx.x;
  float az[8] = {0}, ar[8] = {0}, an0[8] = {0}, an1[8] = {0};
  for (int k = 0; k < 128; ++k) {
    float wz = Wz[(128 + k) * 128 + c];
    float wr = Wr[(128 + k) * 128 + c];
    float w0 = Wn[(128 + k) * 256 + c];
    float w1 = Wn[(128 + k) * 256 + 128 + c];
#pragma unroll
    for (int r = 0; r < 8; ++r) {
      float x = xl[r][k];
      az[r] += x * wz; ar[r] += x * wr; an0[r] += x * w0; an1[r] += x * w1;
    }
  }
  for (int r = 0; r < 8; ++r) {
    size_t base = (size_t)((t0 + r) * BB + b) * 516;
    xdot[base + c] = az[r] + bz[c];
    xdot[base + 128 + c] = ar[r] + br[c];
    xdot[base + 256 + c] = an0[r] + bn[c];
    xdot[base + 384 + c] = an1[r] + bn[128 + c];
  }
  if (threadIdx.x < 8) {
    int r = threadIdx.x;
    float acc = 0.f;
    for (int k = 0; k < 128; ++k) acc += xl[r][k] * Wo[128 + k];
    xdot[(size_t)((t0 + r) * BB + b) * 516 + 512] = acc + bo[0];
  }
}

// -------------------- the scan: 256 WGs x 512 thr, 8 particles/WG --------------------
// R14 frame (batch-per-XCD, k-split-8, flush-free barrier, sc1 h1/lp stores,
// de-transcendentalized B1) + REDUNDANT PER-WAVE B1: every wave polls the counter
// and computes the full resample in registers (idx/wn/pl via shfl) -> removes two
// __syncthreads and the wave0->LDS broadcast from the per-step serial chain.
__global__ __attribute__((amdgpu_waves_per_eu(2, 2))) __launch_bounds__(512) void scan_kernel(
    const float* __restrict__ h0, const float* __restrict__ eps, const float* __restrict__ u_in,
    const float* __restrict__ Wo, const float* __restrict__ Wlab, const float* __restrict__ blab,
    const float* __restrict__ WzrH, const float* __restrict__ WnH, const float* __restrict__ xdot,
    float* __restrict__ h1buf, double* __restrict__ lpbuf, float* __restrict__ ybuf,
    float* __restrict__ pf_out, unsigned* __restrict__ counters) {
  const int tid = threadIdx.x;
  const int bid = blockIdx.x;
  const int b = bid & 31;   // batch -> 8 WGs of a batch share an XCD
  const int wg = bid >> 5;  // 0..7, owns particles 8*wg .. 8*wg+7

  __shared__ float part[8][8][256];  // [ks][row][col] partial sums (64 KB)
  __shared__ float hl[8][132];       // gathered h, row-major
  __shared__ float hT[128][8];       // gathered h, transposed (GEMM operand)
  __shared__ float rhl[8][132];      // r*h row-major
  __shared__ float rhT[128][8];      // r*h transposed (GEMM operand)
  __shared__ float xdl[520];
  __shared__ float wol[128];
  __shared__ float wll[384];
  __shared__ float bll[4];

  unsigned* cnt = counters + b * 64;  // 256 B apart

  const int ks = tid >> 6;   // wave id: k-slice in GEMM, row in reduce, particle in lp
  const int l = tid & 63;
  const int d_ = tid & 127;
  const int rp = tid >> 7;   // 0..3 -> rows 2rp, 2rp+1

  if (tid < 128) wol[tid] = Wo[tid];
  if (tid >= 128 && tid < 512) wll[tid - 128] = Wlab[tid - 128];
  if (tid < 4) bll[tid] = (tid < 3) ? blab[tid] : 0.f;
  float pl_mine = LOG_P0;  // prev log-weight of this wave's particle (8wg+ks)
  int myidx = l;           // resample index for particle l (identity pre-B1)
  float mywn = 0.f;        // new weight for particle l
  {
    float v0 = h0[(size_t)((8 * wg + 2 * rp) * BB + b) * HH + d_];
    float v1 = h0[(size_t)((8 * wg + 2 * rp + 1) * BB + b) * HH + d_];
    hl[2 * rp][d_] = v0;
    hl[2 * rp + 1][d_] = v1;
    *(float2*)&hT[d_][2 * rp] = make_float2(v0, v1);
  }
  if (tid < 129)
    *(float4*)&xdl[tid * 4] = *(const float4*)&xdot[(size_t)(0 * BB + b) * 516 + tid * 4];

  // eps prefetch for t=0: lane l<32 of wave ks holds dims 4l..4l+3 of particle 8wg+ks
  float4 ep4 = make_float4(0.f, 0.f, 0.f, 0.f);
  if (l < 32)
    ep4 = *(const float4*)&eps[((size_t)0 * PB + (size_t)(8 * wg + ks) * BB + b) * HH + 4 * l];
  __syncthreads();

  for (int t = 0; t < TT; ++t) {
    const int par = t & 1;
    float z0, z1, z2, z3;  // gate registers (lanes l<32), set in A1-reduce

    // ---- A1 GEMM: z|r = h @ WzrH. wave ks: k in [16ks,16ks+16); lane l: cols 4l..4l+3
    {
      float a[8][4];
#pragma unroll
      for (int r = 0; r < 8; ++r)
#pragma unroll
        for (int j = 0; j < 4; ++j) a[r][j] = 0.f;
      const float* wp = WzrH + (size_t)(16 * ks) * 256 + 4 * l;
#pragma unroll
      for (int kk = 0; kk < 16; ++kk) {
        float4 w4 = *(const float4*)(wp + kk * 256);
        float4 hA = *(const float4*)&hT[16 * ks + kk][0];
        float4 hB = *(const float4*)&hT[16 * ks + kk][4];
        a[0][0] += hA.x * w4.x; a[0][1] += hA.x * w4.y; a[0][2] += hA.x * w4.z; a[0][3] += hA.x * w4.w;
        a[1][0] += hA.y * w4.x; a[1][1] += hA.y * w4.y; a[1][2] += hA.y * w4.z; a[1][3] += hA.y * w4.w;
        a[2][0] += hA.z * w4.x; a[2][1] += hA.z * w4.y; a[2][2] += hA.z * w4.z; a[2][3] += hA.z * w4.w;
        a[3][0] += hA.w * w4.x; a[3][1] += hA.w * w4.y; a[3][2] += hA.w * w4.z; a[3][3] += hA.w * w4.w;
        a[4][0] += hB.x * w4.x; a[4][1] += hB.x * w4.y; a[4][2] += hB.x * w4.z; a[4][3] += hB.x * w4.w;
        a[5][0] += hB.y * w4.x; a[5][1] += hB.y * w4.y; a[5][2] += hB.y * w4.z; a[5][3] += hB.y * w4.w;
        a[6][0] += hB.z * w4.x; a[6][1] += hB.z * w4.y; a[6][2] += hB.z * w4.z; a[6][3] += hB.z * w4.w;
        a[7][0] += hB.w * w4.x; a[7][1] += hB.w * w4.y; a[7][2] += hB.w * w4.z; a[7][3] += hB.w * w4.w;
      }
#pragma unroll
      for (int r = 0; r < 8; ++r)
        *(float4*)&part[ks][r][4 * l] = make_float4(a[r][0], a[r][1], a[r][2], a[r][3]);
    }
    __syncthreads();

    // ---- A1 reduce + activate
    {
      int c0 = 4 * l;
      float s0 = 0.f, s1 = 0.f, s2 = 0.f, s3 = 0.f;
#pragma unroll
      for (int kq = 0; kq < 8; ++kq) {
        float4 p4 = *(const float4*)&part[kq][ks][c0];
        s0 += p4.x; s1 += p4.y; s2 += p4.z; s3 += p4.w;
      }
      s0 = sigf(s0 + xdl[c0 + 0]);
      s1 = sigf(s1 + xdl[c0 + 1]);
      s2 = sigf(s2 + xdl[c0 + 2]);
      s3 = sigf(s3 + xdl[c0 + 3]);
      if (l < 32) {
        z0 = s0; z1 = s1; z2 = s2; z3 = s3;
      } else {
        int cc = c0 - 128;
        float4 rh4;
        rh4.x = s0 * hl[ks][cc + 0];
        rh4.y = s1 * hl[ks][cc + 1];
        rh4.z = s2 * hl[ks][cc + 2];
        rh4.w = s3 * hl[ks][cc + 3];
        *(float4*)&rhl[ks][cc] = rh4;
      }
    }
    __syncthreads();

    // ---- transpose r*h -> rhT
    {
      float t0v = rhl[2 * rp][d_];
      float t1v = rhl[2 * rp + 1][d_];
      *(float2*)&rhT[d_][2 * rp] = make_float2(t0v, t1v);
    }
    __syncthreads();

    // ---- A2 GEMM: n = (r*h) @ WnH
    {
      float a[8][4];
#pragma unroll
      for (int r = 0; r < 8; ++r)
#pragma unroll
        for (int j = 0; j < 4; ++j) a[r][j] = 0.f;
      const float* wp = WnH + (size_t)(16 * ks) * 256 + 4 * l;
#pragma unroll
      for (int kk = 0; kk < 16; ++kk) {
        float4 w4 = *(const float4*)(wp + kk * 256);
        float4 hA = *(const float4*)&rhT[16 * ks + kk][0];
        float4 hB = *(const float4*)&rhT[16 * ks + kk][4];
        a[0][0] += hA.x * w4.x; a[0][1] += hA.x * w4.y; a[0][2] += hA.x * w4.z; a[0][3] += hA.x * w4.w;
        a[1][0] += hA.y * w4.x; a[1][1] += hA.y * w4.y; a[1][2] += hA.y * w4.z; a[1][3] += hA.y * w4.w;
        a[2][0] += hA.z * w4.x; a[2][1] += hA.z * w4.y; a[2][2] += hA.z * w4.z; a[2][3] += hA.z * w4.w;
        a[3][0] += hA.w * w4.x; a[3][1] += hA.w * w4.y; a[3][2] += hA.w * w4.z; a[3][3] += hA.w * w4.w;
        a[4][0] += hB.x * w4.x; a[4][1] += hB.x * w4.y; a[4][2] += hB.x * w4.z; a[4][3] += hB.x * w4.w;
        a[5][0] += hB.y * w4.x; a[5][1] += hB.y * w4.y; a[5][2] += hB.y * w4.z; a[5][3] += hB.y * w4.w;
        a[6][0] += hB.z * w4.x; a[6][1] += hB.z * w4.y; a[6][2] += hB.z * w4.z; a[6][3] += hB.z * w4.w;
        a[7][0] += hB.w * w4.x; a[7][1] += hB.w * w4.y; a[7][2] += hB.w * w4.z; a[7][3] += hB.w * w4.w;
      }
#pragma unroll
      for (int r = 0; r < 8; ++r)
        *(float4*)&part[ks][r][4 * l] = make_float4(a[r][0], a[r][1], a[r][2], a[r][3]);
    }
    __syncthreads();

    // ---- A2 reduce + FUSED gate/reparam/h1-store/lp (wave ks = particle 8wg+ks)
    {
      int c0 = 4 * l;
      float s0 = 0.f, s1 = 0.f, s2 = 0.f, s3 = 0.f;
#pragma unroll
      for (int kq = 0; kq < 8; ++kq) {
        float4 p4 = *(const float4*)&part[kq][ks][c0];
        s0 += p4.x; s1 += p4.y; s2 += p4.z; s3 += p4.w;
      }
      s0 += xdl[256 + c0 + 0];
      s1 += xdl[256 + c0 + 1];
      s2 += xdl[256 + c0 + 2];
      s3 += xdl[256 + c0 + 3];
      float va0 = __shfl(s0, l + 32);
      float va1 = __shfl(s1, l + 32);
      float va2 = __shfl(s2, l + 32);
      float va3 = __shfl(s3, l + 32);
      double lpacc = 0.0;
      if (l < 32) {
        float4 h4 = *(const float4*)&hl[ks][c0];
        float sp0 = fmaxf(va0, 0.f) + log1pf(expf(-fabsf(va0)));
        float sp1 = fmaxf(va1, 0.f) + log1pf(expf(-fabsf(va1)));
        float sp2 = fmaxf(va2, 0.f) + log1pf(expf(-fabsf(va2)));
        float sp3 = fmaxf(va3, 0.f) + log1pf(expf(-fabsf(va3)));
        float h10 = (1.f - z0) * (s0 + ep4.x * sp0) + z0 * h4.x;
        float h11 = (1.f - z1) * (s1 + ep4.y * sp1) + z1 * h4.y;
        float h12 = (1.f - z2) * (s2 + ep4.z * sp2) + z2 * h4.z;
        float h13 = (1.f - z3) * (s3 + ep4.w * sp3) + z3 * h4.w;
        union { unsigned long long u[2]; float f[4]; } pk;
        pk.f[0] = h10; pk.f[1] = h11; pk.f[2] = h12; pk.f[3] = h13;
        unsigned long long* dst = (unsigned long long*)
            &h1buf[((size_t)par * PB + (size_t)(8 * wg + ks) * BB + b) * HH + c0];
        stc(dst + 0, pk.u[0]);
        stc(dst + 1, pk.u[1]);
        lpacc = (double)h10 * (double)wol[c0 + 0] + (double)h11 * (double)wol[c0 + 1] +
                (double)h12 * (double)wol[c0 + 2] + (double)h13 * (double)wol[c0 + 3];
      }
#pragma unroll
      for (int o = 16; o > 0; o >>= 1) lpacc += __shfl_xor(lpacc, o);
      if (l == 0)
        stc(&lpbuf[par * PB + b * 64 + (8 * wg + ks)],
            lpacc + (double)xdl[512] + (double)pl_mine);
    }

    // ---- prefetch next step's xdot + eps + u (complete during barrier drain)
    const int tn = (t + 1 < TT) ? (t + 1) : t;
    float4 xpf = make_float4(0.f, 0.f, 0.f, 0.f);
    if (tid < 129) xpf = *(const float4*)&xdot[(size_t)(tn * BB + b) * 516 + tid * 4];
    if (l < 32)
      ep4 = *(const float4*)&eps[((size_t)tn * PB + (size_t)(8 * wg + ks) * BB + b) * HH + 4 * l];
    float uval = u_in[((size_t)t * BB + b) * 64 + l];  // B1(t) input, all waves

    // ---- barrier arrival: own sc1 stores drained, whole WG done, then publish
    asm volatile("s_waitcnt vmcnt(0)" ::: "memory");
    __syncthreads();
    if (tid == 0)
      __hip_atomic_fetch_add(cnt, 1u, __ATOMIC_RELAXED, __HIP_MEMORY_SCOPE_AGENT);

    if (tid < 129) *(float4*)&xdl[tid * 4] = xpf;  // xdl consumers all pre-barrier

    // ---- all-lane poll: each wave proceeds the moment the counter trips
    {
      const unsigned tgt = (unsigned)(WGPB * (t + 1));
      unsigned v;
      do {
        __builtin_amdgcn_s_sleep(1);
        v = __hip_atomic_load(cnt, __ATOMIC_RELAXED, __HIP_MEMORY_SCOPE_AGENT);
      } while (v < tgt);
    }
    asm volatile("" ::: "memory");

    // ---- B1: redundant per-wave resampling (f64, registers only; 1 exp + 2 log)
    {
      double lp = ldc(&lpbuf[par * PB + b * 64 + l]);
      double m = lp;
#pragma unroll
      for (int o = 32; o > 0; o >>= 1) m = fmax(m, __shfl_xor(m, o));
      double e = exp(lp - m);
      double s = e;
#pragma unroll
      for (int o = 32; o > 0; o >>= 1) s += __shfl_xor(s, o);
      double els_v = e / s;                       // == exp(log_softmax)
      double w = 0.5 * els_v + INV_P;
      double run = w;
#pragma unroll
      for (int o = 1; o < 64; o <<= 1) {
        double v = __shfl_up(run, o);
        if (l >= o) run += v;
      }
      double ctot = __shfl(run, 63);
      double uv = (double)uval * ctot;
      int idx = 0;
#pragma unroll 8
      for (int i = 0; i < 64; ++i) {
        double ci = __shfl(run, i);
        idx += (ci < uv) ? 1 : 0;
      }
      if (idx > 63) idx = 63;
      myidx = idx;
      double pg = __shfl(els_v, idx);
      double wg_ = 0.5 * pg + INV_P;
      double S2 = wg_;
#pragma unroll
      for (int o = 32; o > 0; o >>= 1) S2 += __shfl_xor(S2, o);
      mywn = (float)(wg_ / S2);
      float pn_l = (float)(log(wg_) - log(S2));
      pl_mine = __shfl(pn_l, 8 * wg + ks);
    }

    // ---- B3: gather resampled h (indices via intra-wave shfl; sc1 loads, L2-hit)
    {
      int a0i = __shfl(myidx, 8 * wg + 2 * rp);
      int a1i = __shfl(myidx, 8 * wg + 2 * rp + 1);
      float v0 = ldc(&h1buf[((size_t)par * PB + (size_t)a0i * BB + b) * HH + d_]);
      float v1 = ldc(&h1buf[((size_t)par * PB + (size_t)a1i * BB + b) * HH + d_]);
      hl[2 * rp][d_] = v0;
      hl[2 * rp + 1][d_] = v1;
      *(float2*)&hT[d_][2 * rp] = make_float2(v0, v1);
    }
    __syncthreads();

    // ---- pf_out projection (wave ks -> particle 8wg+ks)
    {
      float ha = hl[ks][l], hb = hl[ks][l + 64];
      float p0 = ha * wll[l * 3 + 0] + hb * wll[(l + 64) * 3 + 0];
      float p1 = ha * wll[l * 3 + 1] + hb * wll[(l + 64) * 3 + 1];
      float p2 = ha * wll[l * 3 + 2] + hb * wll[(l + 64) * 3 + 2];
#pragma unroll
      for (int o = 32; o > 0; o >>= 1) {
        p0 += __shfl_xor(p0, o); p1 += __shfl_xor(p1, o); p2 += __shfl_xor(p2, o);
      }
      if (l == 0) {
        size_t base = ((size_t)t * PB + (size_t)(8 * wg + ks) * BB + b) * 3;
        pf_out[base + 0] = sigf(p0 + bll[0]);
        pf_out[base + 1] = sigf(p1 + bll[1]);
        pf_out[base + 2] = sigf(p2 + bll[2]);
      }
    }

    // ---- B4: y partial from OWN gathered particles: y += sum_r wn[8wg+r]*h_gathered[r]
    if (tid < 128) {
      float acc = 0.f;
#pragma unroll
      for (int r = 0; r < 8; ++r) acc += __shfl(mywn, 8 * wg + r) * hl[r][tid];
      atomicAdd(&ybuf[((size_t)t * BB + b) * HH + tid], acc);
    }
  }
}

// -------------------- final y_out projection --------------------
__global__ __launch_bounds__(256) void yout_kernel(const float* __restrict__ ybuf,
                                                   const float* __restrict__ Wl,
                                                   const float* __restrict__ bl,
                                                   float* __restrict__ out) {
  __shared__ float wls[384];
  __shared__ float bls[3];
  int tid = threadIdx.x;
  for (int i = tid; i < 384; i += 256) wls[i] = Wl[i];
  if (tid < 3) bls[tid] = bl[tid];
  __syncthreads();
  int wv = tid >> 6, ln = tid & 63;
#pragma unroll
  for (int rr = 0; rr < 2; ++rr) {
    int rowi = blockIdx.x * 8 + wv * 2 + rr;  // < 8192
    float ya = ybuf[(size_t)rowi * 128 + ln];
    float yb = ybuf[(size_t)rowi * 128 + ln + 64];
    float p0 = ya * wls[ln * 3 + 0] + yb * wls[(ln + 64) * 3 + 0];
    float p1 = ya * wls[ln * 3 + 1] + yb * wls[(ln + 64) * 3 + 1];
    float p2 = ya * wls[ln * 3 + 2] + yb * wls[(ln + 64) * 3 + 2];
#pragma unroll
    for (int o = 32; o > 0; o >>= 1) {
      p0 += __shfl_xor(p0, o); p1 += __shfl_xor(p1, o); p2 += __shfl_xor(p2, o);
    }
    if (ln == 0) {
      out[(size_t)rowi * 3 + 0] = 1.f / (1.f + expf(-(p0 + bls[0])));
      out[(size_t)rowi * 3 + 1] = 1.f / (1.f + expf(-(p1 + bls[1])));
      out[(size_t)rowi * 3 + 2] = 1.f / (1.f + expf(-(p2 + bls[2])));
    }
  }
}

}  // namespace

extern "C" void kernel_launch(void* const* d_in, const int* in_sizes, int n_in,
                              void* d_out, int out_size, void* d_ws, size_t ws_size,
                              hipStream_t stream) {
  const float* map_in = (const float*)d_in[0];
  const float* meas_in = (const float*)d_in[1];
  const float* mot_in = (const float*)d_in[2];
  const float* h0 = (const float*)d_in[3];
  const float* eps = (const float*)d_in[4];
  const float* u = (const float*)d_in[5];
  const float* c1w = (const float*)d_in[6];
  const float* c2w = (const float*)d_in[7];
  const float* c3w = (const float*)d_in[8];
  const float* Wme = (const float*)d_in[9];
  const float* bme = (const float*)d_in[10];
  const float* Wmm = (const float*)d_in[11];
  const float* bmm = (const float*)d_in[12];
  const float* Wmo = (const float*)d_in[13];
  const float* bmo = (const float*)d_in[14];
  const float* Wms = (const float*)d_in[15];
  const float* bms = (const float*)d_in[16];
  const float* Wmt = (const float*)d_in[17];
  const float* bmt = (const float*)d_in[18];
  const float* Wz = (const float*)d_in[19];
  const float* bz = (const float*)d_in[20];
  const float* Wr = (const float*)d_in[21];
  const float* br = (const float*)d_in[22];
  const float* Wn = (const float*)d_in[23];
  const float* bn = (const float*)d_in[24];
  const float* Wo = (const float*)d_in[25];
  const float* bo = (const float*)d_in[26];
  const float* Wl = (const float*)d_in[27];
  const float* bl = (const float*)d_in[28];

  // workspace layout (bytes, 16B aligned)
  char* ws = (char*)d_ws;
  unsigned* counters = (unsigned*)(ws + 0);              // 8192 (32 x 256B)
  float* WzrH = (float*)(ws + 8192);                     // 131072
  float* WnH = (float*)(ws + 139264);                    // 131072
  float* emb = (float*)(ws + 270336);                    // 4 MB
  float* xdot = (float*)(ws + 4464640);                  // 16.9 MB
  float* h1buf = (float*)(ws + 21372928);                // 2 MB
  double* lpbuf = (double*)(ws + 23470080);              // 32 KB
  float* ybuf = (float*)(ws + 23502848);                 // 4 MB; end = 27697152
  if (ws_size < 27697152) return;

  float* out = (float*)d_out;
  float* pf_out = out + 24576;  // y_out is 256*32*3

  hipMemsetAsync(counters, 0, 8192, stream);
  hipMemsetAsync(ybuf, 0, 4194304, stream);  // accumulated via atomicAdd in scan
  hipLaunchKernelGGL(pack_kernel, dim3(128), dim3(256), 0, stream, Wz, Wr, Wn, WzrH, WnH);
  hipLaunchKernelGGL(encode_kernel, dim3(32), dim3(256), 0, stream, map_in, meas_in, mot_in,
                     c1w, c2w, c3w, Wme, bme, Wmm, bmm, Wmo, bmo, Wms, bms, Wmt, bmt, emb);
  hipLaunchKernelGGL(xdot_kernel, dim3(32, 32), dim3(128), 0, stream, emb, Wz, Wr, Wn, bz, br,
                     bn, Wo, bo, xdot);
  hipLaunchKernelGGL(scan_kernel, dim3(256), dim3(512), 0, stream, h0, eps, u, Wo, Wl, bl,
                     WzrH, WnH, xdot, h1buf, lpbuf, ybuf, pf_out, counters);
  hipLaunchKernelGGL(yout_kernel, dim3(1024), dim3(256), 0, stream, ybuf, Wl, bl, out);
}

// Round 18
// 5249.164 us; speedup vs baseline: 1.2622x; 1.2622x over previous
//
#include <hip/hip_runtime.h>
#include <cmath>

namespace {

constexpr int BB = 32, TT = 256, HH = 128;
constexpr int PB = 2048;                   // B*P
constexpr int WGPB = 8;                    // workgroups per batch
constexpr double INV_P = 0.0078125;        // (1-alpha)/P
constexpr float LOG_P0 = -4.1588830833596715f;  // log(1/64)

__device__ __forceinline__ float sigf(float x) { return 1.f / (1.f + expf(-x)); }

// coherent (agent-scope, non-invalidating/non-flushing) ops for cross-WG data
__device__ __forceinline__ float ldc(const float* p) {
  return __hip_atomic_load(p, __ATOMIC_RELAXED, __HIP_MEMORY_SCOPE_AGENT);
}
__device__ __forceinline__ double ldc(const double* p) {
  return __hip_atomic_load(p, __ATOMIC_RELAXED, __HIP_MEMORY_SCOPE_AGENT);
}
__device__ __forceinline__ void stc(unsigned long long* p, unsigned long long v) {
  __hip_atomic_store(p, v, __ATOMIC_RELAXED, __HIP_MEMORY_SCOPE_AGENT);
}
__device__ __forceinline__ void stc(double* p, double v) {
  __hip_atomic_store(p, v, __ATOMIC_RELAXED, __HIP_MEMORY_SCOPE_AGENT);
}

// ---- pack: WzrH[k][c] (k<128, c<256), WnH[k][c] ----
__global__ void pack_kernel(const float* __restrict__ Wz, const float* __restrict__ Wr,
                            const float* __restrict__ Wn,
                            float* __restrict__ WzrH, float* __restrict__ WnH) {
  int tid = blockIdx.x * blockDim.x + threadIdx.x;
  int stride = gridDim.x * blockDim.x;
  for (int i = tid; i < 128 * 256; i += stride) {
    int k = i >> 8, c = i & 255;
    WzrH[i] = (c < 128) ? Wz[k * 128 + c] : Wr[k * 128 + (c - 128)];
    WnH[i] = Wn[k * 256 + c];
  }
}

// -------------------- encode: convs + map/meas/mot embeddings -> emb[b][t][128] ----
__global__ __launch_bounds__(256) void encode_kernel(
    const float* __restrict__ map_in, const float* __restrict__ meas_in,
    const float* __restrict__ mot_in,
    const float* __restrict__ c1w, const float* __restrict__ c2w, const float* __restrict__ c3w,
    const float* __restrict__ Wme, const float* __restrict__ bme,
    const float* __restrict__ Wmm, const float* __restrict__ bmm,
    const float* __restrict__ Wmo, const float* __restrict__ bmo,
    const float* __restrict__ Wms, const float* __restrict__ bms,
    const float* __restrict__ Wmt, const float* __restrict__ bmt,
    float* __restrict__ emb) {
  const int b = blockIdx.x;
  const int tid = threadIdx.x;
  __shared__ float ml[324];
  __shared__ float o1[16 * 81];
  __shared__ float o2[32 * 81];
  __shared__ float o3[32 * 81];
  __shared__ float em[128];
  __shared__ float mm[64];
  __shared__ float mo[64];

  for (int i = tid; i < 324; i += 256) ml[i] = map_in[b * 324 + i];
  __syncthreads();
  for (int oid = tid; oid < 16 * 81; oid += 256) {
    int c = oid / 81, r = oid % 81, i = r / 9, j = r % 9;
    float acc = 0.f;
    for (int u = 0; u < 5; ++u) {
      int ii = 2 * i - 2 + u;
      if (ii < 0 || ii >= 18) continue;
      for (int v = 0; v < 5; ++v) {
        int jj = 2 * j - 2 + v;
        if (jj < 0 || jj >= 18) continue;
        acc += ml[ii * 18 + jj] * c1w[c * 25 + u * 5 + v];
      }
    }
    o1[oid] = fmaxf(acc, 0.f);
  }
  __syncthreads();
  for (int oid = tid; oid < 32 * 81; oid += 256) {
    int c = oid / 81, r = oid % 81, i = r / 9, j = r % 9;
    float acc = 0.f;
    for (int ci = 0; ci < 16; ++ci)
      for (int u = 0; u < 3; ++u) {
        int ii = i + u - 1;
        if (ii < 0 || ii >= 9) continue;
        for (int v = 0; v < 3; ++v) {
          int jj = j + v - 1;
          if (jj < 0 || jj >= 9) continue;
          acc += o1[ci * 81 + ii * 9 + jj] * c2w[((c * 16 + ci) * 3 + u) * 3 + v];
        }
      }
    o2[oid] = fmaxf(acc, 0.f);
  }
  __syncthreads();
  for (int oid = tid; oid < 32 * 81; oid += 256) {
    int c = oid / 81, r = oid % 81, i = r / 9, j = r % 9;
    float acc = 0.f;
    for (int ci = 0; ci < 32; ++ci)
      for (int u = 0; u < 3; ++u) {
        int ii = i + u - 1;
        if (ii < 0 || ii >= 9) continue;
        for (int v = 0; v < 3; ++v) {
          int jj = j + v - 1;
          if (jj < 0 || jj >= 9) continue;
          acc += o2[ci * 81 + ii * 9 + jj] * c3w[((c * 32 + ci) * 3 + u) * 3 + v];
        }
      }
    o3[oid] = fmaxf(acc, 0.f);
  }
  __syncthreads();
  if (tid < 128) {
    float acc = 0.f;
    for (int k = 0; k < 2592; ++k) acc += o3[k] * Wme[k * 128 + tid];
    em[tid] = fmaxf(acc + bme[tid], 0.f);
  }
  __syncthreads();
  if (tid < 64) {
    float a1 = 0.f, a2 = 0.f;
    for (int k = 0; k < 128; ++k) {
      a1 += em[k] * Wmm[k * 64 + tid];
      a2 += em[k] * Wmo[k * 64 + tid];
    }
    mm[tid] = fmaxf(a1 + bmm[tid], 0.f);
    mo[tid] = fmaxf(a2 + bmo[tid], 0.f);
  }
  __syncthreads();
  {
    int c = tid & 127;
    for (int t = tid >> 7; t < TT; t += 2) {
      float e;
      if (c < 64) {
        float acc = 0.f;
        for (int m = 0; m < 16; ++m) acc += meas_in[(size_t)(b * TT + t) * 16 + m] * Wms[m * 64 + c];
        e = fmaxf(acc + bms[c], 0.f) * mm[c];
      } else {
        int c2 = c - 64;
        float acc = 0.f;
        for (int m = 0; m < 3; ++m) acc += mot_in[(size_t)(b * TT + t) * 3 + m] * Wmt[m * 64 + c2];
        e = fmaxf(acc + bmt[c2], 0.f) * mo[c2];
      }
      emb[(size_t)(b * TT + t) * 128 + c] = e;
    }
  }
}

// ---------- xdot: per-(t,b) x-part of each GEMM column + bias -> xdot[t][b][516] ----
__global__ __launch_bounds__(128) void xdot_kernel(
    const float* __restrict__ emb, const float* __restrict__ Wz, const float* __restrict__ Wr,
    const float* __restrict__ Wn, const float* __restrict__ bz, const float* __restrict__ br,
    const float* __restrict__ bn, const float* __restrict__ Wo, const float* __restrict__ bo,
    float* __restrict__ xdot) {
  const int b = blockIdx.y;
  const int t0 = blockIdx.x * 8;
  __shared__ float xl[8][132];
  for (int i = threadIdx.x; i < 8 * 128; i += 128) {
    int r = i >> 7, d = i & 127;
    xl[r][d] = emb[(size_t)(b * TT + t0 + r) * 128 + d];
  }
  __syncthreads();
  const int c = threadIdx.x;
  float az[8] = {0}, ar[8] = {0}, an0[8] = {0}, an1[8] = {0};
  for (int k = 0; k < 128; ++k) {
    float wz = Wz[(128 + k) * 128 + c];
    float wr = Wr[(128 + k) * 128 + c];
    float w0 = Wn[(128 + k) * 256 + c];
    float w1 = Wn[(128 + k) * 256 + 128 + c];
#pragma unroll
    for (int r = 0; r < 8; ++r) {
      float x = xl[r][k];
      az[r] += x * wz; ar[r] += x * wr; an0[r] += x * w0; an1[r] += x * w1;
    }
  }
  for (int r = 0; r < 8; ++r) {
    size_t base = (size_t)((t0 + r) * BB + b) * 516;
    xdot[base + c] = az[r] + bz[c];
    xdot[base + 128 + c] = ar[r] + br[c];
    xdot[base + 256 + c] = an0[r] + bn[c];
    xdot[base + 384 + c] = an1[r] + bn[128 + c];
  }
  if (threadIdx.x < 8) {
    int r = threadIdx.x;
    float acc = 0.f;
    for (int k = 0; k < 128; ++k) acc += xl[r][k] * Wo[128 + k];
    xdot[(size_t)((t0 + r) * BB + b) * 516 + 512] = acc + bo[0];
  }
}

// ---- device-scope batch barrier: no cache-maintenance ops (R11 protocol) ----
__device__ __forceinline__ void batch_barrier(unsigned* cnt, unsigned target) {
  asm volatile("s_waitcnt vmcnt(0)" ::: "memory");  // own sc1 stores at coherence point
  __syncthreads();
  if (threadIdx.x == 0) {
    __hip_atomic_fetch_add(cnt, 1u, __ATOMIC_RELAXED, __HIP_MEMORY_SCOPE_AGENT);
    unsigned v;
    do {
      __builtin_amdgcn_s_sleep(1);
      v = __hip_atomic_load(cnt, __ATOMIC_RELAXED, __HIP_MEMORY_SCOPE_AGENT);
    } while (v < target);
  }
  asm volatile("" ::: "memory");
  __syncthreads();
}

// -------------------- the scan: 256 WGs x 512 thr, 8 particles/WG --------------------
// R11 base (batch-per-XCD, k-split-8, clean flush-free barrier, sc1 h1/lp stores)
// + de-transcendentalized B1 (1 exp + 2 log; els via shfl).
__global__ __attribute__((amdgpu_waves_per_eu(2, 2))) __launch_bounds__(512) void scan_kernel(
    const float* __restrict__ h0, const float* __restrict__ eps, const float* __restrict__ u_in,
    const float* __restrict__ Wo, const float* __restrict__ Wlab, const float* __restrict__ blab,
    const float* __restrict__ WzrH, const float* __restrict__ WnH, const float* __restrict__ xdot,
    float* __restrict__ h1buf, double* __restrict__ lpbuf, float* __restrict__ ybuf,
    float* __restrict__ pf_out, unsigned* __restrict__ counters) {
  const int tid = threadIdx.x;
  const int bid = blockIdx.x;
  const int b = bid & 31;   // batch -> 8 WGs of a batch share an XCD (bid mod 8 = b mod 8)
  const int wg = bid >> 5;  // 0..7, owns particles 8*wg .. 8*wg+7

  __shared__ float part[8][8][256];  // [ks][row][col] partial sums (64 KB)
  __shared__ float hl[8][132];       // gathered h, row-major
  __shared__ float hT[128][8];       // gathered h, transposed (GEMM operand)
  __shared__ float rhl[8][132];      // r*h row-major
  __shared__ float rhT[128][8];      // r*h transposed (GEMM operand)
  __shared__ float xdl[520];
  __shared__ float wol[128];
  __shared__ float wll[384];
  __shared__ float bll[4];
  __shared__ double cdl[64];
  __shared__ float wnl[64];
  __shared__ int idxl[64];
  __shared__ float pl[8];

  unsigned* cnt = counters + b * 64;  // 256 B apart

  const int ks = tid >> 6;   // wave id: k-slice in GEMM, row in reduce, particle in lp
  const int l = tid & 63;
  const int d_ = tid & 127;
  const int rp = tid >> 7;   // 0..3 -> rows 2rp, 2rp+1

  if (tid < 128) wol[tid] = Wo[tid];
  if (tid >= 128 && tid < 512) wll[tid - 128] = Wlab[tid - 128];
  if (tid < 4) bll[tid] = (tid < 3) ? blab[tid] : 0.f;
  if (tid < 8) pl[tid] = LOG_P0;
  {
    float v0 = h0[(size_t)((8 * wg + 2 * rp) * BB + b) * HH + d_];
    float v1 = h0[(size_t)((8 * wg + 2 * rp + 1) * BB + b) * HH + d_];
    hl[2 * rp][d_] = v0;
    hl[2 * rp + 1][d_] = v1;
    *(float2*)&hT[d_][2 * rp] = make_float2(v0, v1);
  }
  if (tid < 129)
    *(float4*)&xdl[tid * 4] = *(const float4*)&xdot[(size_t)(0 * BB + b) * 516 + tid * 4];

  // eps prefetch for t=0: lane l<32 of wave ks holds dims 4l..4l+3 of particle 8wg+ks
  float4 ep4 = make_float4(0.f, 0.f, 0.f, 0.f);
  if (l < 32)
    ep4 = *(const float4*)&eps[((size_t)0 * PB + (size_t)(8 * wg + ks) * BB + b) * HH + 4 * l];
  __syncthreads();

  for (int t = 0; t < TT; ++t) {
    const int par = t & 1;
    float z0, z1, z2, z3;  // gate registers (lanes l<32), set in A1-reduce

    // ---- A1 GEMM: z|r = h @ WzrH. wave ks: k in [16ks,16ks+16); lane l: cols 4l..4l+3
    {
      float a[8][4];
#pragma unroll
      for (int r = 0; r < 8; ++r)
#pragma unroll
        for (int j = 0; j < 4; ++j) a[r][j] = 0.f;
      const float* wp = WzrH + (size_t)(16 * ks) * 256 + 4 * l;
#pragma unroll
      for (int kk = 0; kk < 16; ++kk) {
        float4 w4 = *(const float4*)(wp + kk * 256);
        float4 hA = *(const float4*)&hT[16 * ks + kk][0];
        float4 hB = *(const float4*)&hT[16 * ks + kk][4];
        a[0][0] += hA.x * w4.x; a[0][1] += hA.x * w4.y; a[0][2] += hA.x * w4.z; a[0][3] += hA.x * w4.w;
        a[1][0] += hA.y * w4.x; a[1][1] += hA.y * w4.y; a[1][2] += hA.y * w4.z; a[1][3] += hA.y * w4.w;
        a[2][0] += hA.z * w4.x; a[2][1] += hA.z * w4.y; a[2][2] += hA.z * w4.z; a[2][3] += hA.z * w4.w;
        a[3][0] += hA.w * w4.x; a[3][1] += hA.w * w4.y; a[3][2] += hA.w * w4.z; a[3][3] += hA.w * w4.w;
        a[4][0] += hB.x * w4.x; a[4][1] += hB.x * w4.y; a[4][2] += hB.x * w4.z; a[4][3] += hB.x * w4.w;
        a[5][0] += hB.y * w4.x; a[5][1] += hB.y * w4.y; a[5][2] += hB.y * w4.z; a[5][3] += hB.y * w4.w;
        a[6][0] += hB.z * w4.x; a[6][1] += hB.z * w4.y; a[6][2] += hB.z * w4.z; a[6][3] += hB.z * w4.w;
        a[7][0] += hB.w * w4.x; a[7][1] += hB.w * w4.y; a[7][2] += hB.w * w4.z; a[7][3] += hB.w * w4.w;
      }
#pragma unroll
      for (int r = 0; r < 8; ++r)
        *(float4*)&part[ks][r][4 * l] = make_float4(a[r][0], a[r][1], a[r][2], a[r][3]);
    }
    __syncthreads();

    // ---- A1 reduce + activate
    {
      int c0 = 4 * l;
      float s0 = 0.f, s1 = 0.f, s2 = 0.f, s3 = 0.f;
#pragma unroll
      for (int kq = 0; kq < 8; ++kq) {
        float4 p4 = *(const float4*)&part[kq][ks][c0];
        s0 += p4.x; s1 += p4.y; s2 += p4.z; s3 += p4.w;
      }
      s0 = sigf(s0 + xdl[c0 + 0]);
      s1 = sigf(s1 + xdl[c0 + 1]);
      s2 = sigf(s2 + xdl[c0 + 2]);
      s3 = sigf(s3 + xdl[c0 + 3]);
      if (l < 32) {
        z0 = s0; z1 = s1; z2 = s2; z3 = s3;
      } else {
        int cc = c0 - 128;
        float4 rh4;
        rh4.x = s0 * hl[ks][cc + 0];
        rh4.y = s1 * hl[ks][cc + 1];
        rh4.z = s2 * hl[ks][cc + 2];
        rh4.w = s3 * hl[ks][cc + 3];
        *(float4*)&rhl[ks][cc] = rh4;
      }
    }
    __syncthreads();

    // ---- transpose r*h -> rhT
    {
      float t0v = rhl[2 * rp][d_];
      float t1v = rhl[2 * rp + 1][d_];
      *(float2*)&rhT[d_][2 * rp] = make_float2(t0v, t1v);
    }
    __syncthreads();

    // ---- A2 GEMM: n = (r*h) @ WnH
    {
      float a[8][4];
#pragma unroll
      for (int r = 0; r < 8; ++r)
#pragma unroll
        for (int j = 0; j < 4; ++j) a[r][j] = 0.f;
      const float* wp = WnH + (size_t)(16 * ks) * 256 + 4 * l;
#pragma unroll
      for (int kk = 0; kk < 16; ++kk) {
        float4 w4 = *(const float4*)(wp + kk * 256);
        float4 hA = *(const float4*)&rhT[16 * ks + kk][0];
        float4 hB = *(const float4*)&rhT[16 * ks + kk][4];
        a[0][0] += hA.x * w4.x; a[0][1] += hA.x * w4.y; a[0][2] += hA.x * w4.z; a[0][3] += hA.x * w4.w;
        a[1][0] += hA.y * w4.x; a[1][1] += hA.y * w4.y; a[1][2] += hA.y * w4.z; a[1][3] += hA.y * w4.w;
        a[2][0] += hA.z * w4.x; a[2][1] += hA.z * w4.y; a[2][2] += hA.z * w4.z; a[2][3] += hA.z * w4.w;
        a[3][0] += hA.w * w4.x; a[3][1] += hA.w * w4.y; a[3][2] += hA.w * w4.z; a[3][3] += hA.w * w4.w;
        a[4][0] += hB.x * w4.x; a[4][1] += hB.x * w4.y; a[4][2] += hB.x * w4.z; a[4][3] += hB.x * w4.w;
        a[5][0] += hB.y * w4.x; a[5][1] += hB.y * w4.y; a[5][2] += hB.y * w4.z; a[5][3] += hB.y * w4.w;
        a[6][0] += hB.z * w4.x; a[6][1] += hB.z * w4.y; a[6][2] += hB.z * w4.z; a[6][3] += hB.z * w4.w;
        a[7][0] += hB.w * w4.x; a[7][1] += hB.w * w4.y; a[7][2] += hB.w * w4.z; a[7][3] += hB.w * w4.w;
      }
#pragma unroll
      for (int r = 0; r < 8; ++r)
        *(float4*)&part[ks][r][4 * l] = make_float4(a[r][0], a[r][1], a[r][2], a[r][3]);
    }
    __syncthreads();

    // ---- A2 reduce + FUSED gate/reparam/h1-store/lp (wave ks = particle 8wg+ks)
    {
      int c0 = 4 * l;
      float s0 = 0.f, s1 = 0.f, s2 = 0.f, s3 = 0.f;
#pragma unroll
      for (int kq = 0; kq < 8; ++kq) {
        float4 p4 = *(const float4*)&part[kq][ks][c0];
        s0 += p4.x; s1 += p4.y; s2 += p4.z; s3 += p4.w;
      }
      s0 += xdl[256 + c0 + 0];
      s1 += xdl[256 + c0 + 1];
      s2 += xdl[256 + c0 + 2];
      s3 += xdl[256 + c0 + 3];
      float va0 = __shfl(s0, l + 32);
      float va1 = __shfl(s1, l + 32);
      float va2 = __shfl(s2, l + 32);
      float va3 = __shfl(s3, l + 32);
      double lpacc = 0.0;
      if (l < 32) {
        float4 h4 = *(const float4*)&hl[ks][c0];
        float sp0 = fmaxf(va0, 0.f) + log1pf(expf(-fabsf(va0)));
        float sp1 = fmaxf(va1, 0.f) + log1pf(expf(-fabsf(va1)));
        float sp2 = fmaxf(va2, 0.f) + log1pf(expf(-fabsf(va2)));
        float sp3 = fmaxf(va3, 0.f) + log1pf(expf(-fabsf(va3)));
        float h10 = (1.f - z0) * (s0 + ep4.x * sp0) + z0 * h4.x;
        float h11 = (1.f - z1) * (s1 + ep4.y * sp1) + z1 * h4.y;
        float h12 = (1.f - z2) * (s2 + ep4.z * sp2) + z2 * h4.z;
        float h13 = (1.f - z3) * (s3 + ep4.w * sp3) + z3 * h4.w;
        union { unsigned long long u[2]; float f[4]; } pk;
        pk.f[0] = h10; pk.f[1] = h11; pk.f[2] = h12; pk.f[3] = h13;
        unsigned long long* dst = (unsigned long long*)
            &h1buf[((size_t)par * PB + (size_t)(8 * wg + ks) * BB + b) * HH + c0];
        stc(dst + 0, pk.u[0]);
        stc(dst + 1, pk.u[1]);
        lpacc = (double)h10 * (double)wol[c0 + 0] + (double)h11 * (double)wol[c0 + 1] +
                (double)h12 * (double)wol[c0 + 2] + (double)h13 * (double)wol[c0 + 3];
      }
#pragma unroll
      for (int o = 16; o > 0; o >>= 1) lpacc += __shfl_xor(lpacc, o);
      if (l == 0)
        stc(&lpbuf[par * PB + b * 64 + (8 * wg + ks)],
            lpacc + (double)xdl[512] + (double)pl[ks]);
    }

    // ---- prefetch next step's xdot + eps (complete during barrier drain)
    const int tn = (t + 1 < TT) ? (t + 1) : t;
    float4 xpf = make_float4(0.f, 0.f, 0.f, 0.f);
    if (tid < 129) xpf = *(const float4*)&xdot[(size_t)(tn * BB + b) * 516 + tid * 4];
    if (l < 32)
      ep4 = *(const float4*)&eps[((size_t)tn * PB + (size_t)(8 * wg + ks) * BB + b) * HH + 4 * l];

    batch_barrier(cnt, (unsigned)(WGPB * (t + 1)));

    if (tid < 129) *(float4*)&xdl[tid * 4] = xpf;

    // ---- B1: de-transcendentalized resampling (wave 0, f64): 1 exp + 2 log
    if (ks == 0) {
      double lp = ldc(&lpbuf[par * PB + b * 64 + l]);
      double m = lp;
#pragma unroll
      for (int o = 32; o > 0; o >>= 1) m = fmax(m, __shfl_xor(m, o));
      double e = exp(lp - m);
      double s = e;
#pragma unroll
      for (int o = 32; o > 0; o >>= 1) s += __shfl_xor(s, o);
      double els_v = e / s;                       // == exp(log_softmax)
      double w = 0.5 * els_v + INV_P;
      double run = w;
#pragma unroll
      for (int o = 1; o < 64; o <<= 1) {
        double v = __shfl_up(run, o);
        if (l >= o) run += v;
      }
      cdl[l] = run;
      double ctot = __shfl(run, 63);
      double uv = (double)u_in[((size_t)t * BB + b) * 64 + l] * ctot;
      int idx = 0;
#pragma unroll 8
      for (int i = 0; i < 64; ++i) idx += (cdl[i] < uv) ? 1 : 0;
      if (idx > 63) idx = 63;
      idxl[l] = idx;
      double pg = __shfl(els_v, idx);
      double wg_ = 0.5 * pg + INV_P;
      double S2 = wg_;
#pragma unroll
      for (int o = 32; o > 0; o >>= 1) S2 += __shfl_xor(S2, o);
      // logsumexp(log wg_) == log(S2); p_new = log(wg_) - log(S2)
      wnl[l] = (float)(wg_ / S2);
      if ((l >> 3) == wg) pl[l & 7] = (float)(log(wg_) - log(S2));
    }
    __syncthreads();

    // ---- B3: gather resampled h (sc1 loads, L2-hit) -> hl + hT (rows 2rp, 2rp+1)
    {
      int a0i = idxl[8 * wg + 2 * rp];
      int a1i = idxl[8 * wg + 2 * rp + 1];
      float v0 = ldc(&h1buf[((size_t)par * PB + (size_t)a0i * BB + b) * HH + d_]);
      float v1 = ldc(&h1buf[((size_t)par * PB + (size_t)a1i * BB + b) * HH + d_]);
      hl[2 * rp][d_] = v0;
      hl[2 * rp + 1][d_] = v1;
      *(float2*)&hT[d_][2 * rp] = make_float2(v0, v1);
    }
    __syncthreads();

    // ---- pf_out projection (wave ks -> particle 8wg+ks)
    {
      float ha = hl[ks][l], hb = hl[ks][l + 64];
      float p0 = ha * wll[l * 3 + 0] + hb * wll[(l + 64) * 3 + 0];
      float p1 = ha * wll[l * 3 + 1] + hb * wll[(l + 64) * 3 + 1];
      float p2 = ha * wll[l * 3 + 2] + hb * wll[(l + 64) * 3 + 2];
#pragma unroll
      for (int o = 32; o > 0; o >>= 1) {
        p0 += __shfl_xor(p0, o); p1 += __shfl_xor(p1, o); p2 += __shfl_xor(p2, o);
      }
      if (l == 0) {
        size_t base = ((size_t)t * PB + (size_t)(8 * wg + ks) * BB + b) * 3;
        pf_out[base + 0] = sigf(p0 + bll[0]);
        pf_out[base + 1] = sigf(p1 + bll[1]);
        pf_out[base + 2] = sigf(p2 + bll[2]);
      }
    }

    // ---- B4: y partial from OWN gathered particles: y += sum_r wn[8wg+r]*h_gathered[r]
    if (tid < 128) {
      float acc = 0.f;
#pragma unroll
      for (int r = 0; r < 8; ++r) acc += wnl[8 * wg + r] * hl[r][tid];
      atomicAdd(&ybuf[((size_t)t * BB + b) * HH + tid], acc);
    }
  }
}

// -------------------- final y_out projection --------------------
__global__ __launch_bounds__(256) void yout_kernel(const float* __restrict__ ybuf,
                                                   const float* __restrict__ Wl,
                                                   const float* __restrict__ bl,
                                                   float* __restrict__ out) {
  __shared__ float wls[384];
  __shared__ float bls[3];
  int tid = threadIdx.x;
  for (int i = tid; i < 384; i += 256) wls[i] = Wl[i];
  if (tid < 3) bls[tid] = bl[tid];
  __syncthreads();
  int wv = tid >> 6, ln = tid & 63;
#pragma unroll
  for (int rr = 0; rr < 2; ++rr) {
    int rowi = blockIdx.x * 8 + wv * 2 + rr;  // < 8192
    float ya = ybuf[(size_t)rowi * 128 + ln];
    float yb = ybuf[(size_t)rowi * 128 + ln + 64];
    float p0 = ya * wls[ln * 3 + 0] + yb * wls[(ln + 64) * 3 + 0];
    float p1 = ya * wls[ln * 3 + 1] + yb * wls[(ln + 64) * 3 + 1];
    float p2 = ya * wls[ln * 3 + 2] + yb * wls[(ln + 64) * 3 + 2];
#pragma unroll
    for (int o = 32; o > 0; o >>= 1) {
      p0 += __shfl_xor(p0, o); p1 += __shfl_xor(p1, o); p2 += __shfl_xor(p2, o);
    }
    if (ln == 0) {
      out[(size_t)rowi * 3 + 0] = 1.f / (1.f + expf(-(p0 + bls[0])));
      out[(size_t)rowi * 3 + 1] = 1.f / (1.f + expf(-(p1 + bls[1])));
      out[(size_t)rowi * 3 + 2] = 1.f / (1.f + expf(-(p2 + bls[2])));
    }
  }
}

}  // namespace

extern "C" void kernel_launch(void* const* d_in, const int* in_sizes, int n_in,
                              void* d_out, int out_size, void* d_ws, size_t ws_size,
                              hipStream_t stream) {
  const float* map_in = (const float*)d_in[0];
  const float* meas_in = (const float*)d_in[1];
  const float* mot_in = (const float*)d_in[2];
  const float* h0 = (const float*)d_in[3];
  const float* eps = (const float*)d_in[4];
  const float* u = (const float*)d_in[5];
  const float* c1w = (const float*)d_in[6];
  const float* c2w = (const float*)d_in[7];
  const float* c3w = (const float*)d_in[8];
  const float* Wme = (const float*)d_in[9];
  const float* bme = (const float*)d_in[10];
  const float* Wmm = (const float*)d_in[11];
  const float* bmm = (const float*)d_in[12];
  const float* Wmo = (const float*)d_in[13];
  const float* bmo = (const float*)d_in[14];
  const float* Wms = (const float*)d_in[15];
  const float* bms = (const float*)d_in[16];
  const float* Wmt = (const float*)d_in[17];
  const float* bmt = (const float*)d_in[18];
  const float* Wz = (const float*)d_in[19];
  const float* bz = (const float*)d_in[20];
  const float* Wr = (const float*)d_in[21];
  const float* br = (const float*)d_in[22];
  const float* Wn = (const float*)d_in[23];
  const float* bn = (const float*)d_in[24];
  const float* Wo = (const float*)d_in[25];
  const float* bo = (const float*)d_in[26];
  const float* Wl = (const float*)d_in[27];
  const float* bl = (const float*)d_in[28];

  // workspace layout (bytes, 16B aligned)
  char* ws = (char*)d_ws;
  unsigned* counters = (unsigned*)(ws + 0);              // 8192 (32 x 256B)
  float* WzrH = (float*)(ws + 8192);                     // 131072
  float* WnH = (float*)(ws + 139264);                    // 131072
  float* emb = (float*)(ws + 270336);                    // 4 MB
  float* xdot = (float*)(ws + 4464640);                  // 16.9 MB
  float* h1buf = (float*)(ws + 21372928);                // 2 MB
  double* lpbuf = (double*)(ws + 23470080);              // 32 KB
  float* ybuf = (float*)(ws + 23502848);                 // 4 MB; end = 27697152
  if (ws_size < 27697152) return;

  float* out = (float*)d_out;
  float* pf_out = out + 24576;  // y_out is 256*32*3

  hipMemsetAsync(counters, 0, 8192, stream);
  hipMemsetAsync(ybuf, 0, 4194304, stream);  // accumulated via atomicAdd in scan
  hipLaunchKernelGGL(pack_kernel, dim3(128), dim3(256), 0, stream, Wz, Wr, Wn, WzrH, WnH);
  hipLaunchKernelGGL(encode_kernel, dim3(32), dim3(256), 0, stream, map_in, meas_in, mot_in,
                     c1w, c2w, c3w, Wme, bme, Wmm, bmm, Wmo, bmo, Wms, bms, Wmt, bmt, emb);
  hipLaunchKernelGGL(xdot_kernel, dim3(32, 32), dim3(128), 0, stream, emb, Wz, Wr, Wn, bz, br,
                     bn, Wo, bo, xdot);
  hipLaunchKernelGGL(scan_kernel, dim3(256), dim3(512), 0, stream, h0, eps, u, Wo, Wl, bl,
                     WzrH, WnH, xdot, h1buf, lpbuf, ybuf, pf_out, counters);
  hipLaunchKernelGGL(yout_kernel, dim3(1024), dim3(256), 0, stream, ybuf, Wl, bl, out);
}